// Round 3
// baseline (302.737 us; speedup 1.0000x reference)
//
#include <hip/hip_runtime.h>
#include <cstdint>
#include <cstddef>

// ---------------------------------------------------------------------------
// MultiHeadAttention: B=4,G=64,N=256,C=256,HEAD=8,HD=32
//   Q=q@wq+bq; K=k@wk+bk; V=v@wv+bv (per (b,g,h): softmax(QK^T/sqrt32) @ V)
//   out = ctx@wo+bo   (fp32 in/out, bf16 MFMA internally)
// ws layout (bf16): Q[64Mrows? no: 65536x256] | K | V | ctx  = 4 * 32MB = 128MB
// ---------------------------------------------------------------------------

typedef __attribute__((ext_vector_type(4))) float f4;
typedef __attribute__((ext_vector_type(8))) short s8;
typedef __attribute__((ext_vector_type(4))) short s4;
typedef unsigned short u16;

__device__ __forceinline__ u16 f2bf(float f) {
    union { float f; uint32_t u; } x{f};
    uint32_t r = (x.u + 0x7FFFu + ((x.u >> 16) & 1u)) >> 16;
    return (u16)r;
}

static constexpr int CD  = 256;   // C
static constexpr int BK  = 64;
static constexpr int LDT = BK + 8;  // +8 bf16 pad: row stride 144B -> banks spread 8-way

// ---------------- GEMM: out[M=grid.y*128][256] = A[.,256] @ W[256][256] + bias
template<bool A_F32, bool OUT_F32>
__global__ __launch_bounds__(256) void gemm_k(const void* __restrict__ Ain,
                                              const float* __restrict__ W,
                                              const float* __restrict__ bias,
                                              void* __restrict__ Out)
{
    __shared__ u16 As[128][LDT];   // [row m][k]
    __shared__ u16 Bs[128][LDT];   // transposed: [col n][k]
    const int t    = threadIdx.x;
    const int lane = t & 63, wid = t >> 6;
    const int m0 = blockIdx.y * 128, n0 = blockIdx.x * 128;
    const int wr = (wid >> 1) * 64, wc = (wid & 1) * 64;
    const int lr = lane & 15, lk = (lane >> 4) * 8;

    f4 acc[4][4] = {};

    for (int k0 = 0; k0 < CD; k0 += BK) {
        // ---- stage A tile 128 x 64 into LDS (convert fp32->bf16 if needed)
        if constexpr (A_F32) {
            const float* A = (const float*)Ain;
            #pragma unroll
            for (int j = 0; j < 8; ++j) {
                int ch = t + j * 256;            // 2048 float4 chunks
                int r = ch >> 4, c4 = ch & 15;   // 16 float4 per row
                f4 f = *(const f4*)(A + (size_t)(m0 + r) * CD + k0 + c4 * 4);
                s4 h = { (short)f2bf(f[0]), (short)f2bf(f[1]),
                         (short)f2bf(f[2]), (short)f2bf(f[3]) };
                *(s4*)&As[r][c4 * 4] = h;
            }
        } else {
            const u16* A = (const u16*)Ain;
            #pragma unroll
            for (int j = 0; j < 4; ++j) {
                int ch = t + j * 256;            // 1024 16B chunks
                int r = ch >> 3, c8 = ch & 7;
                *(s8*)&As[r][c8 * 8] =
                    *(const s8*)(A + (size_t)(m0 + r) * CD + k0 + c8 * 8);
            }
        }
        // ---- stage W tile 64 x 128, transposed into Bs[n][k]
        #pragma unroll
        for (int j = 0; j < 8; ++j) {
            int ch = t + j * 256;
            int k = ch >> 5, nc = ch & 31;       // 32 float4 per k-row
            f4 f = *(const f4*)(W + (size_t)(k0 + k) * CD + n0 + nc * 4);
            #pragma unroll
            for (int i = 0; i < 4; ++i) Bs[nc * 4 + i][k] = f2bf(f[i]);
        }
        __syncthreads();

        #pragma unroll
        for (int kk = 0; kk < BK; kk += 32) {
            s8 a[4], b[4];
            #pragma unroll
            for (int m = 0; m < 4; ++m)
                a[m] = *(const s8*)&As[wr + m * 16 + lr][kk + lk];
            #pragma unroll
            for (int n = 0; n < 4; ++n)
                b[n] = *(const s8*)&Bs[wc + n * 16 + lr][kk + lk];
            #pragma unroll
            for (int m = 0; m < 4; ++m)
                #pragma unroll
                for (int n = 0; n < 4; ++n)
                    acc[m][n] = __builtin_amdgcn_mfma_f32_16x16x32_bf16(
                        a[m], b[n], acc[m][n], 0, 0, 0);
        }
        __syncthreads();
    }

    // ---- epilogue: D[row=4*(l>>4)+r][col=l&15]
    const int orow = (lane >> 4) * 4;
    #pragma unroll
    for (int m = 0; m < 4; ++m) {
        #pragma unroll
        for (int n = 0; n < 4; ++n) {
            int col = n0 + wc + n * 16 + lr;
            float bv = bias[col];
            #pragma unroll
            for (int r = 0; r < 4; ++r) {
                int row = m0 + wr + m * 16 + orow + r;
                float v = acc[m][n][r] + bv;
                if constexpr (OUT_F32)
                    ((float*)Out)[(size_t)row * CD + col] = v;
                else
                    ((u16*)Out)[(size_t)row * CD + col] = f2bf(v);
            }
        }
    }
}

// ---------------- fused attention per (b,g,h, 64-row q-block)
// grid: x = rb + 4*h (32), y = g (64), z = b (4); 256 threads = 4 waves,
// wave w owns q-rows [rb*64 + w*16, +16).
__global__ __launch_bounds__(256) void attn_k(const u16* __restrict__ Q,
                                              const u16* __restrict__ K,
                                              const u16* __restrict__ V,
                                              u16* __restrict__ Ctx)
{
    __shared__ u16 Qs[64][40];       // [qrow][d]   stride 80B
    __shared__ u16 Ks[256][40];      // [krow][d]
    __shared__ u16 Vt[32][264];      // [d][krow]   stride 528B
    __shared__ u16 Ps[4][16][264];   // per-wave P strip [qrow][krow]

    const int bx = blockIdx.x;
    const int rb = bx & 3, h = bx >> 2;
    const int g = blockIdx.y, b = blockIdx.z;
    const int t = threadIdx.x, lane = t & 63, w = t >> 6;
    const size_t base = (size_t)(b * 64 + g) * 65536 + (size_t)h * 32;

    // stage Q (64x32)
    {
        int r = t >> 2, cc = (t & 3) * 8;
        *(s8*)&Qs[r][cc] = *(const s8*)(Q + base + (size_t)(rb * 64 + r) * CD + cc);
    }
    // stage K (256x32)
    #pragma unroll
    for (int it = 0; it < 4; ++it) {
        int r = it * 64 + (t >> 2), cc = (t & 3) * 8;
        *(s8*)&Ks[r][cc] = *(const s8*)(K + base + (size_t)r * CD + cc);
    }
    // stage V transposed (d-major)
    #pragma unroll
    for (int it = 0; it < 4; ++it) {
        int n = it * 64 + (t >> 2), cc = (t & 3) * 8;
        s8 v = *(const s8*)(V + base + (size_t)n * CD + cc);
        #pragma unroll
        for (int i = 0; i < 8; ++i) Vt[cc + i][n] = (u16)v[i];
    }
    __syncthreads();

    const int lr = lane & 15, lk = (lane >> 4) * 8;
    const int orow = (lane >> 4) * 4;

    // S = Q K^T  (hd = 32 = exactly one mfma K-step)
    s8 aq = *(const s8*)&Qs[w * 16 + lr][lk];
    f4 zero = {0.f, 0.f, 0.f, 0.f};
    f4 s[16];
    #pragma unroll
    for (int j = 0; j < 16; ++j) {
        s8 bk = *(const s8*)&Ks[j * 16 + lr][lk];
        s[j] = __builtin_amdgcn_mfma_f32_16x16x32_bf16(aq, bk, zero, 0, 0, 0);
    }

    const float inv_scale = 1.0f / (sqrtf(32.0f) + 1e-8f);
    float mrow[4] = {-3.0e38f, -3.0e38f, -3.0e38f, -3.0e38f};
    #pragma unroll
    for (int j = 0; j < 16; ++j)
        #pragma unroll
        for (int r = 0; r < 4; ++r) {
            s[j][r] *= inv_scale;
            mrow[r] = fmaxf(mrow[r], s[j][r]);
        }
    #pragma unroll
    for (int d = 1; d < 16; d <<= 1)
        #pragma unroll
        for (int r = 0; r < 4; ++r)
            mrow[r] = fmaxf(mrow[r], __shfl_xor(mrow[r], d));

    float lsum[4] = {0.f, 0.f, 0.f, 0.f};
    #pragma unroll
    for (int j = 0; j < 16; ++j)
        #pragma unroll
        for (int r = 0; r < 4; ++r) {
            float p = __expf(s[j][r] - mrow[r]);
            s[j][r] = p;
            lsum[r] += p;
        }
    #pragma unroll
    for (int d = 1; d < 16; d <<= 1)
        #pragma unroll
        for (int r = 0; r < 4; ++r)
            lsum[r] += __shfl_xor(lsum[r], d);

    // P: D-layout -> LDS -> A-layout
    #pragma unroll
    for (int j = 0; j < 16; ++j)
        #pragma unroll
        for (int r = 0; r < 4; ++r)
            Ps[w][orow + r][j * 16 + lr] = f2bf(s[j][r]);
    __syncthreads();

    // ctx = P @ V   (K = 256 keys, 8 mfma steps x 2 col-frags)
    f4 o[2] = {};
    #pragma unroll
    for (int kk = 0; kk < 8; ++kk) {
        s8 ap = *(const s8*)&Ps[w][lr][kk * 32 + lk];
        #pragma unroll
        for (int c = 0; c < 2; ++c) {
            s8 bv = *(const s8*)&Vt[c * 16 + lr][kk * 32 + lk];
            o[c] = __builtin_amdgcn_mfma_f32_16x16x32_bf16(ap, bv, o[c], 0, 0, 0);
        }
    }

    #pragma unroll
    for (int c = 0; c < 2; ++c)
        #pragma unroll
        for (int r = 0; r < 4; ++r) {
            float val = o[c][r] / lsum[r];
            int qrow = rb * 64 + w * 16 + orow + r;
            Ctx[base + (size_t)qrow * CD + c * 16 + lr] = f2bf(val);
        }
}

extern "C" void kernel_launch(void* const* d_in, const int* in_sizes, int n_in,
                              void* d_out, int out_size, void* d_ws, size_t ws_size,
                              hipStream_t stream) {
    const float* q  = (const float*)d_in[0];
    const float* k  = (const float*)d_in[1];
    const float* v  = (const float*)d_in[2];
    const float* wq = (const float*)d_in[3];
    const float* bq = (const float*)d_in[4];
    const float* wk = (const float*)d_in[5];
    const float* bk = (const float*)d_in[6];
    const float* wv = (const float*)d_in[7];
    const float* bv = (const float*)d_in[8];
    const float* wo = (const float*)d_in[9];
    const float* bo = (const float*)d_in[10];
    float* out = (float*)d_out;

    const size_t E = (size_t)65536 * 256;  // elements per intermediate
    u16* Qb = (u16*)d_ws;
    u16* Kb = Qb + E;
    u16* Vb = Kb + E;
    u16* Cx = Vb + E;
    // requires ws_size >= 4*E*2 = 128 MB

    dim3 gg(2, 512);
    gemm_k<true,  false><<<gg, 256, 0, stream>>>(q, wq, bq, Qb);
    gemm_k<true,  false><<<gg, 256, 0, stream>>>(k, wk, bk, Kb);
    gemm_k<true,  false><<<gg, 256, 0, stream>>>(v, wv, bv, Vb);
    attn_k<<<dim3(32, 64, 4), 256, 0, stream>>>(Qb, Kb, Vb, Cx);
    gemm_k<false, true ><<<gg, 256, 0, stream>>>(Cx, wo, bo, out);
}

// Round 4
// 186.090 us; speedup vs baseline: 1.6268x; 1.6268x over previous
//
#include <hip/hip_runtime.h>
#include <hip/hip_bf16.h>
#include <cstdint>
#include <cstddef>

// B=4,G=64,N=256,C=256,HEAD=8,HD=32
// out = softmax((q@wq+bq)(k@wk+bk)^T / sqrt(32)) @ (v@wv+bv) @ wo + bo
// Pipeline: prep (W^T->bf16, Q-scale folded) -> fused QKV GEMM -> attn -> O GEMM
// ws (bf16): Qb | Kb | Vb | WT(4x256x256)   ; ctx aliases Qb (disjoint r/w order)

typedef __attribute__((ext_vector_type(4))) float f4;
typedef __attribute__((ext_vector_type(8))) short s8;
typedef __attribute__((ext_vector_type(4))) short s4;
typedef unsigned short u16;

#define AS1 __attribute__((address_space(1)))
#define AS3 __attribute__((address_space(3)))

static constexpr int CD = 256;

__device__ __forceinline__ u16 f2bf(float f) {
    __hip_bfloat16 h = __float2bfloat16(f);   // RNE; compiler emits cvt op
    return *reinterpret_cast<u16*>(&h);
}

__device__ __forceinline__ void gload_lds16(const void* g, void* l) {
    __builtin_amdgcn_global_load_lds((const AS1 uint32_t*)g, (AS3 uint32_t*)l, 16, 0, 0);
}

// ---------------- prep: WT[n][k] = W[k][n] as bf16; wq pre-scaled by qs ------
__global__ __launch_bounds__(256) void prep_k(const float* __restrict__ wq,
                                              const float* __restrict__ wk,
                                              const float* __restrict__ wv,
                                              const float* __restrict__ wo,
                                              u16* __restrict__ WT, float qs)
{
    const int bx = blockIdx.x;                 // 64 blocks: 4 weights x 16 tiles
    const int wsel = bx >> 4, tl = bx & 15;
    const int k0 = (tl & 3) * 64, n0 = (tl >> 2) * 64;
    const float* W = wsel == 0 ? wq : wsel == 1 ? wk : wsel == 2 ? wv : wo;
    const float scale = wsel == 0 ? qs : 1.0f;
    u16* dst = WT + (size_t)wsel * 65536;
    __shared__ float T[64][65];
    const int t = threadIdx.x;
    const int rr = t >> 4, c0 = (t & 15) * 4;
    #pragma unroll
    for (int i = 0; i < 4; ++i) {
        int r = i * 16 + rr;
        f4 f = *(const f4*)(W + (size_t)(k0 + r) * CD + n0 + c0);
        #pragma unroll
        for (int j = 0; j < 4; ++j) T[c0 + j][r] = f[j] * scale;
    }
    __syncthreads();
    #pragma unroll
    for (int i = 0; i < 4; ++i) {
        int n = i * 16 + rr;
        s4 h;
        #pragma unroll
        for (int j = 0; j < 4; ++j) h[j] = (short)f2bf(T[n][c0 + j]);
        *(s4*)(dst + (size_t)(n0 + n) * CD + k0 + c0) = h;
    }
}

// ---------------- GEMM body: Out[m0:+128][n0:+128] = A @ WT^T + bias*escale --
// LDS [128][64] bf16, XOR-swizzled (elem ^= (row&7)<<3 within row) both sides.
template<bool A_F32, bool OUT_F32>
__device__ __forceinline__ void gemm_body(const void* __restrict__ Ain,
                                          const u16* __restrict__ Wt,
                                          const float* __restrict__ bias,
                                          float escale, void* __restrict__ Out,
                                          int d)
{
    __shared__ u16 As[128 * 64];
    __shared__ u16 Bs[128 * 64];
    const int n0 = (d >> 9) * 128;       // pair (d, d+512) shares m0 -> same XCD
    const int m0 = (d & 511) * 128;
    const int t = threadIdx.x, lane = t & 63, w = t >> 6;
    const int wr = (w >> 1) * 64, wc = (w & 1) * 64;
    const int lr = lane & 15, lk = (lane >> 4) * 8;

    f4 acc[4][4] = {};

    for (int k0 = 0; k0 < CD; k0 += 64) {
        // B: 16KB via global_load_lds, source pre-swizzled
        #pragma unroll
        for (int j = 0; j < 4; ++j) {
            int c = j * 4 + w;
            int row = c * 8 + (lane >> 3);
            int col = ((lane & 7) * 8) ^ ((row & 7) << 3);
            gload_lds16(Wt + (size_t)(n0 + row) * CD + k0 + col,
                        &Bs[c * 512 + lane * 8]);
        }
        if constexpr (A_F32) {           // reg-staged convert, swizzled write
            const float* A = (const float*)Ain;
            #pragma unroll
            for (int j = 0; j < 4; ++j) {
                int ch = t + j * 256;
                int r = ch >> 3, c8 = ch & 7;
                const float* src = A + (size_t)(m0 + r) * CD + k0 + c8 * 8;
                f4 f0 = *(const f4*)src;
                f4 f1 = *(const f4*)(src + 4);
                s8 h;
                #pragma unroll
                for (int i = 0; i < 4; ++i) {
                    h[i]     = (short)f2bf(f0[i]);
                    h[i + 4] = (short)f2bf(f1[i]);
                }
                *(s8*)&As[r * 64 + ((c8 * 8) ^ ((r & 7) << 3))] = h;
            }
        } else {
            const u16* A = (const u16*)Ain;
            #pragma unroll
            for (int j = 0; j < 4; ++j) {
                int c = j * 4 + w;
                int row = c * 8 + (lane >> 3);
                int col = ((lane & 7) * 8) ^ ((row & 7) << 3);
                gload_lds16(A + (size_t)(m0 + row) * CD + k0 + col,
                            &As[c * 512 + lane * 8]);
            }
        }
        __syncthreads();

        #pragma unroll
        for (int kk = 0; kk < 64; kk += 32) {
            s8 a[4], b[4];
            #pragma unroll
            for (int m = 0; m < 4; ++m) {
                int R = wr + m * 16 + lr;
                a[m] = *(const s8*)&As[R * 64 + ((kk + lk) ^ ((R & 7) << 3))];
            }
            #pragma unroll
            for (int n = 0; n < 4; ++n) {
                int R = wc + n * 16 + lr;
                b[n] = *(const s8*)&Bs[R * 64 + ((kk + lk) ^ ((R & 7) << 3))];
            }
            #pragma unroll
            for (int m = 0; m < 4; ++m)
                #pragma unroll
                for (int n = 0; n < 4; ++n)
                    acc[m][n] = __builtin_amdgcn_mfma_f32_16x16x32_bf16(
                        a[m], b[n], acc[m][n], 0, 0, 0);
        }
        __syncthreads();
    }

    const int orow = (lane >> 4) * 4;
    #pragma unroll
    for (int n = 0; n < 4; ++n) {
        int col = n0 + wc + n * 16 + lr;
        float bb = bias[col] * escale;
        #pragma unroll
        for (int m = 0; m < 4; ++m)
            #pragma unroll
            for (int r = 0; r < 4; ++r) {
                int row = m0 + wr + m * 16 + orow + r;
                float v = acc[m][n][r] + bb;
                if constexpr (OUT_F32)
                    ((float*)Out)[(size_t)row * CD + col] = v;
                else
                    ((u16*)Out)[(size_t)row * CD + col] = f2bf(v);
            }
    }
}

__global__ __launch_bounds__(256, 3) void gemmqkv_k(const float* q, const float* k,
        const float* v, const u16* WT, const float* bq, const float* bk,
        const float* bv, float qs, u16* Qb, u16* Kb, u16* Vb)
{
    const int op = blockIdx.x >> 10;     // 0=q 1=k 2=v (1024 % 8 == 0: XCD safe)
    const int d  = blockIdx.x & 1023;
    const float* A    = op == 0 ? q  : op == 1 ? k  : v;
    const u16*   Wt   = WT + (size_t)op * 65536;
    const float* bias = op == 0 ? bq : op == 1 ? bk : bv;
    u16*         Out  = op == 0 ? Qb : op == 1 ? Kb : Vb;
    gemm_body<true, false>(A, Wt, bias, op == 0 ? qs : 1.0f, Out, d);
}

__global__ __launch_bounds__(256, 3) void gemmo_k(const u16* Cx, const u16* WT,
                                                  const float* bo, float* out)
{
    gemm_body<false, true>(Cx, WT, bo, 1.0f, out, blockIdx.x);
}

// ---------------- attn: one block per (b,g,h); 4 waves x 64 q-rows ----------
// Q pre-scaled by log2e/sqrt(hd) (folded into Wq) -> softmax via exp2.
__global__ __launch_bounds__(256, 3) void attn_k(const u16* Qb,
                                                 const u16* __restrict__ Kb,
                                                 const u16* __restrict__ Vb,
                                                 u16* Ctx)   // Ctx aliases Qb!
{
    __shared__ u16 Ks[256 * 32];       // swizzled rows of 32 elems, 16 KB
    __shared__ u16 Vt[32][260];        // [d][krow], 16.25 KB
    __shared__ u16 Ps[4][16][132];     // per-wave half-strip, 16.5 KB
    const int d = blockIdx.x;          // h*256 + bg: all h of a (b,g) same XCD
    const int bg = d & 255, h = d >> 8;
    const size_t base = (size_t)bg * (256 * 256) + h * 32;
    const int t = threadIdx.x, lane = t & 63, w = t >> 6;
    const int lr = lane & 15, lk = (lane >> 4) * 8;
    const int orow = (lane >> 4) * 4;

    // stage K (swizzled global_load_lds: slot ^= ((row>>1)&3)<<3)
    #pragma unroll
    for (int j = 0; j < 4; ++j) {
        int c = j * 4 + w;
        int row = c * 16 + (lane >> 2);
        int col = ((lane & 3) * 8) ^ (((row >> 1) & 3) << 3);
        gload_lds16(Kb + base + (size_t)row * CD + col, &Ks[c * 512 + lane * 8]);
    }
    // stage V transposed: each thread one 4x8 block, vectorized s4 column writes
    {
        int n0 = (t >> 2) * 4, c0 = (t & 3) * 8;
        const u16* vp = Vb + base + (size_t)n0 * CD + c0;
        s8 r0 = *(const s8*)(vp);
        s8 r1 = *(const s8*)(vp + CD);
        s8 r2 = *(const s8*)(vp + 2 * CD);
        s8 r3 = *(const s8*)(vp + 3 * CD);
        #pragma unroll
        for (int i = 0; i < 8; ++i) {
            s4 cv = { r0[i], r1[i], r2[i], r3[i] };
            *(s4*)&Vt[c0 + i][n0] = cv;
        }
    }
    // hoist all Q fragments (must precede any Ctx write: Ctx aliases Qb)
    s8 aq[4];
    #pragma unroll
    for (int m = 0; m < 4; ++m)
        aq[m] = *(const s8*)(Qb + base + (size_t)(w * 64 + m * 16 + lr) * CD + lk);

    __syncthreads();

    const int myslot = lk ^ (((lr >> 1) & 3) << 3);
    const f4 zero = {0.f, 0.f, 0.f, 0.f};

    #pragma unroll
    for (int m = 0; m < 4; ++m) {
        // S = Q K^T  (16 q-rows x 256 k)
        f4 s[16];
        #pragma unroll
        for (int j = 0; j < 16; ++j) {
            s8 bk = *(const s8*)&Ks[(j * 16 + lr) * 32 + myslot];
            s[j] = __builtin_amdgcn_mfma_f32_16x16x32_bf16(aq[m], bk, zero, 0, 0, 0);
        }
        // softmax over k (base-2 domain; scale folded into Q)
        float mrow[4] = {-3.0e38f, -3.0e38f, -3.0e38f, -3.0e38f};
        #pragma unroll
        for (int j = 0; j < 16; ++j)
            #pragma unroll
            for (int r = 0; r < 4; ++r) mrow[r] = fmaxf(mrow[r], s[j][r]);
        #pragma unroll
        for (int dd = 1; dd < 16; dd <<= 1)
            #pragma unroll
            for (int r = 0; r < 4; ++r) mrow[r] = fmaxf(mrow[r], __shfl_xor(mrow[r], dd));
        float lsum[4] = {0.f, 0.f, 0.f, 0.f};
        #pragma unroll
        for (int j = 0; j < 16; ++j)
            #pragma unroll
            for (int r = 0; r < 4; ++r) {
                float p = exp2f(s[j][r] - mrow[r]);
                s[j][r] = p;
                lsum[r] += p;
            }
        #pragma unroll
        for (int dd = 1; dd < 16; dd <<= 1)
            #pragma unroll
            for (int r = 0; r < 4; ++r) lsum[r] += __shfl_xor(lsum[r], dd);

        // PV in two halves through per-wave Ps strip (no barrier: wave-local)
        f4 o0 = zero, o1 = zero;
        #pragma unroll
        for (int half = 0; half < 2; ++half) {
            #pragma unroll
            for (int j = 0; j < 8; ++j)
                #pragma unroll
                for (int r = 0; r < 4; ++r)
                    Ps[w][orow + r][j * 16 + lr] = f2bf(s[half * 8 + j][r]);
            #pragma unroll
            for (int kk = 0; kk < 4; ++kk) {
                s8 ap  = *(const s8*)&Ps[w][lr][kk * 32 + lk];
                s8 bv0 = *(const s8*)&Vt[lr][(half * 4 + kk) * 32 + lk];
                s8 bv1 = *(const s8*)&Vt[16 + lr][(half * 4 + kk) * 32 + lk];
                o0 = __builtin_amdgcn_mfma_f32_16x16x32_bf16(ap, bv0, o0, 0, 0, 0);
                o1 = __builtin_amdgcn_mfma_f32_16x16x32_bf16(ap, bv1, o1, 0, 0, 0);
            }
        }
        // store ctx rows (writes into Qb region owned by this wave's rows)
        #pragma unroll
        for (int r = 0; r < 4; ++r) {
            float inv = __builtin_amdgcn_rcpf(lsum[r]);
            int row = w * 64 + m * 16 + orow + r;
            Ctx[base + (size_t)row * CD + lr]      = f2bf(o0[r] * inv);
            Ctx[base + (size_t)row * CD + 16 + lr] = f2bf(o1[r] * inv);
        }
    }
}

extern "C" void kernel_launch(void* const* d_in, const int* in_sizes, int n_in,
                              void* d_out, int out_size, void* d_ws, size_t ws_size,
                              hipStream_t stream) {
    const float* q  = (const float*)d_in[0];
    const float* k  = (const float*)d_in[1];
    const float* v  = (const float*)d_in[2];
    const float* wq = (const float*)d_in[3];
    const float* bq = (const float*)d_in[4];
    const float* wk = (const float*)d_in[5];
    const float* bk = (const float*)d_in[6];
    const float* wv = (const float*)d_in[7];
    const float* bv = (const float*)d_in[8];
    const float* wo = (const float*)d_in[9];
    const float* bo = (const float*)d_in[10];
    float* out = (float*)d_out;

    const size_t E = (size_t)65536 * 256;
    u16* Qb = (u16*)d_ws;
    u16* Kb = Qb + E;
    u16* Vb = Kb + E;
    u16* WT = Vb + E;          // 4*65536 u16 = 512 KB; total ws = 96.5 MB
    u16* Cx = Qb;              // ctx aliases Qb (safe: per-wave hoisted Q reads)

    const float qs = (1.0f / (sqrtf(32.0f) + 1e-8f)) * 1.4426950408889634f;

    prep_k<<<64, 256, 0, stream>>>(wq, wk, wv, wo, WT, qs);
    gemmqkv_k<<<3072, 256, 0, stream>>>(q, k, v, WT, bq, bk, bv, qs, Qb, Kb, Vb);
    attn_k<<<2048, 256, 0, stream>>>(Qb, Kb, Vb, Cx);
    gemmo_k<<<1024, 256, 0, stream>>>(Cx, WT + 3 * 65536, bo, out);
}